// Round 8
// baseline (10222.194 us; speedup 1.0000x reference)
//
#include <hip/hip_runtime.h>

// Problem constants (from reference)
#define SEQ   8192
#define HID   256
#define G3    768      // 3*HID
#define TSTART 1024    // SEQ/8
#define NEGD  1365     // SEQ/6
#define TCNT  5791     // (SEQ - 10 - NEGD - 4 + 2) - TSTART
#define DENOMF 23164.0f // TCNT*4

typedef _Float16 half2_t __attribute__((ext_vector_type(2)));

__device__ __forceinline__ float fdot2(half2_t a, half2_t b, float c) {
#if __has_builtin(__builtin_amdgcn_fdot2)
  return __builtin_amdgcn_fdot2(a, b, c, false);
#else
  return c + (float)a.x * (float)b.x + (float)a.y * (float)b.y;
#endif
}

__device__ __forceinline__ half2_t h2u(unsigned int u) {
  return __builtin_bit_cast(half2_t, u);
}

__device__ __forceinline__ float sigmoidf_fast(float x) {
  return 1.0f / (1.0f + __expf(-x));
}
// tanh via sigmoid form: safe at both extremes (exp under/overflow -> +-1)
__device__ __forceinline__ float tanhf_fast(float x) {
  return 2.0f / (1.0f + __expf(-2.0f * x)) - 1.0f;
}

// ---------------------------------------------------------------------------
// init: zero the loss accumulators (ws is poisoned 0xAA every call)
// ---------------------------------------------------------------------------
__global__ void init_kernel(float* accum) {
  if (threadIdx.x < 2) accum[threadIdx.x] = 0.0f;
}

// ---------------------------------------------------------------------------
// wcvt: pre-convert Whh f32 -> packed f16 pairs, row-major:
// wpk[o*128 + p] = (W[o][2p], W[o][2p+1]). gru thread i loads its row as
// 32 contiguous uint4.
// ---------------------------------------------------------------------------
__global__ __launch_bounds__(256) void wcvt_kernel(
    const float* __restrict__ Whh, unsigned* __restrict__ wpk)
{
  int u = blockIdx.x * 256 + threadIdx.x;   // 98304 packed pairs
  int o = u >> 7, p = u & 127;
  _Float16 lo = (_Float16)Whh[(size_t)o * 256 + 2 * p];
  _Float16 hi = (_Float16)Whh[(size_t)o * 256 + 2 * p + 1];
  half2_t pr; pr.x = lo; pr.y = hi;
  wpk[u] = __builtin_bit_cast(unsigned, pr);
}

// ---------------------------------------------------------------------------
// Phase A: xW = data @ Wih^T + bih -> f32 [SEQ][768]. All f32.
// grid (256, 3), block 256. Thread owns output col o; 32-row x-tile in LDS.
// ---------------------------------------------------------------------------
__global__ __launch_bounds__(256) void xw_kernel(
    const float* __restrict__ data, const float* __restrict__ Wih,
    const float* __restrict__ bih, float* __restrict__ xw)
{
  __shared__ float4 xs4[32 * 64];   // 32 rows x 256 f32 = 32 KB
  const int o  = blockIdx.y * 256 + threadIdx.x;
  const int m0 = blockIdx.x * 32;

  float* xsf = (float*)xs4;
  for (int r = 0; r < 32; ++r)
    xsf[r * 256 + threadIdx.x] = data[(size_t)(m0 + r) * 256 + threadIdx.x];
  __syncthreads();

  const float b = bih[o];
  float acc[32];
#pragma unroll
  for (int r = 0; r < 32; ++r) acc[r] = b;

  const float4* wrow = (const float4*)(Wih + (size_t)o * 256);
  for (int kc = 0; kc < 4; ++kc) {
    float4 w[16];
#pragma unroll
    for (int j = 0; j < 16; ++j) w[j] = wrow[kc * 16 + j];
#pragma unroll
    for (int r = 0; r < 32; ++r) {
      const float4* xr = xs4 + r * 64 + kc * 16;
      float a0 = 0.f, a1 = 0.f, a2 = 0.f, a3 = 0.f;
#pragma unroll
      for (int j = 0; j < 4; ++j) {
        float4 x0 = xr[4 * j + 0], x1 = xr[4 * j + 1];
        float4 x2 = xr[4 * j + 2], x3 = xr[4 * j + 3];
        float4 w0 = w[4 * j + 0], w1 = w[4 * j + 1];
        float4 w2 = w[4 * j + 2], w3 = w[4 * j + 3];
        a0 = fmaf(w0.x, x0.x, fmaf(w0.y, x0.y, fmaf(w0.z, x0.z, fmaf(w0.w, x0.w, a0))));
        a1 = fmaf(w1.x, x1.x, fmaf(w1.y, x1.y, fmaf(w1.z, x1.z, fmaf(w1.w, x1.w, a1))));
        a2 = fmaf(w2.x, x2.x, fmaf(w2.y, x2.y, fmaf(w2.z, x2.z, fmaf(w2.w, x2.w, a2))));
        a3 = fmaf(w3.x, x3.x, fmaf(w3.y, x3.y, fmaf(w3.z, x3.z, fmaf(w3.w, x3.w, a3))));
      }
      acc[r] += (a0 + a1) + (a2 + a3);
    }
  }
  for (int r = 0; r < 32; ++r)
    xw[(size_t)(m0 + r) * G3 + o] = acc[r];
}

// ---------------------------------------------------------------------------
// data row norms: one wave per row (f32 data)
// ---------------------------------------------------------------------------
__global__ __launch_bounds__(256) void rnorm_kernel(
    const float* __restrict__ data, float* __restrict__ rn)
{
  int wave = threadIdx.x >> 6, lane = threadIdx.x & 63;
  int row = blockIdx.x * 4 + wave;
  const float* xr = data + (size_t)row * HID;
  float a = xr[lane], b = xr[lane + 64], c = xr[lane + 128], d = xr[lane + 192];
  float s = a * a + b * b + c * c + d * d;
#pragma unroll
  for (int off = 32; off; off >>= 1) s += __shfl_xor(s, off, 64);
  if (lane == 0) rn[row] = fmaxf(sqrtf(s), 1e-8f);
}

// ---------------------------------------------------------------------------
// Phase B: sequential GRU scan. ONE block, 768 threads (12 waves, 3/SIMD,
// 170-reg budget). Thread i=(g,c) owns the FULL row g*256+c as 32 uint4 =
// 128 packed-f16 regs (well under budget -- r4/r6/r7 showed the allocator
// halves weight arrays that approach the budget into AGPRs, costing a
// v_accvgpr_read per dot). Full-row ownership kills the partial exchange:
// each thread produces a complete pre-activation; g=1/2 publish one f32,
// g=0 threads do the gate math. One coalesced xw load per thread per step.
// ---------------------------------------------------------------------------
__global__ __launch_bounds__(768, 3) void gru_kernel(
    const unsigned* __restrict__ wpk, const float* __restrict__ bhh,
    const float* __restrict__ xw, float* __restrict__ zout)
{
  __shared__ uint4 hpk[32];                 // h as 256 packed f16
  __shared__ float preZ[256], preN[256], xnS[256];
  const int i = threadIdx.x;
  const int c = i & 255, g = i >> 8;        // g in {0,1,2}

  // --- weights: this thread's full row, 32 uint4 -> 128 arch VGPRs ---
  uint4 wq[32];
  {
    const uint4* wp = (const uint4*)wpk + (size_t)i * 32;
#pragma unroll
    for (int j = 0; j < 32; ++j) wq[j] = wp[j];
  }
  const float bias = bhh[i];

  if (i < 32) hpk[i] = make_uint4(0u, 0u, 0u, 0u);
  __syncthreads();

  float hreg = 0.0f;                        // live in g==0 threads
  float xv = xw[i];                         // step 0, coalesced

  for (int s = 0; s < SEQ; ++s) {
    // next step's xw element (one coalesced load; L2 latency hidden)
    float xv_next = xw[(size_t)(s + 1 < SEQ ? s + 1 : s) * G3 + i];

    // --- full-row dot against h (wave-uniform LDS broadcast reads) ---
    float a0 = bias + ((g < 2) ? xv : 0.0f);   // fold bias (+xr/xz) into acc
    float a1 = 0.f, a2 = 0.f, a3 = 0.f;
#pragma unroll
    for (int j = 0; j < 32; ++j) {
      uint4 hj = hpk[j];
      a0 = fdot2(h2u(wq[j].x), h2u(hj.x), a0);
      a1 = fdot2(h2u(wq[j].y), h2u(hj.y), a1);
      a2 = fdot2(h2u(wq[j].z), h2u(hj.z), a2);
      a3 = fdot2(h2u(wq[j].w), h2u(hj.w), a3);
    }
    float pre = (a0 + a1) + (a2 + a3);

    if (g == 1)      preZ[c] = pre;                      // z preact (+bz+xz)
    else if (g == 2) { preN[c] = pre; xnS[c] = xv; }     // n preact (+bn), xn
    __syncthreads();

    if (g == 0) {   // waves 0-3: gate math + h update (non-redundant)
      float rg = sigmoidf_fast(pre);                     // r preact (+br+xr)
      float zg = sigmoidf_fast(preZ[c]);
      float ng = tanhf_fast(xnS[c] + rg * preN[c]);
      hreg = (1.0f - zg) * ng + zg * hreg;
      ((_Float16*)hpk)[c] = (_Float16)hreg;
      zout[(size_t)s * HID + c] = hreg;
    }
    __syncthreads();
    xv = xv_next;
  }
}

// ---------------------------------------------------------------------------
// Phase C: NCE loss + accuracy. One block per t, 4 waves = 4 timespans.
// Reads f32 z straight from d_out.
// ---------------------------------------------------------------------------
__global__ __launch_bounds__(256) void cpc_kernel(
    const float* __restrict__ x, const float* __restrict__ zf,
    const float* __restrict__ rn, float* __restrict__ accum)
{
  __shared__ float zsh[HID];
  __shared__ float wsum[4];
  __shared__ float nce_s[4], acc_s[4];
  const int tt = TSTART + blockIdx.x;
  const int i = threadIdx.x;
  const int wave = i >> 6, lane = i & 63;

  float zi = zf[(size_t)tt * HID + i];
  zsh[i] = zi;
  float p = zi * zi;
#pragma unroll
  for (int off = 32; off; off >>= 1) p += __shfl_xor(p, off, 64);
  if (lane == 0) wsum[wave] = p;
  __syncthreads();
  float zn = fmaxf(sqrtf(wsum[0] + wsum[1] + wsum[2] + wsum[3]), 1e-8f);

  float z0 = zsh[lane], z1 = zsh[lane + 64], z2 = zsh[lane + 128], z3 = zsh[lane + 192];
  const int base = tt + wave + 1;   // pos index for timespan (wave+1)

  float tot[10];
#pragma unroll
  for (int n = 0; n < 10; ++n) {
    int idx = base + (n > 0 ? (NEGD + n - 1) : 0);
    const float* xr = x + (size_t)idx * HID;
    float q = xr[lane] * z0 + xr[lane + 64] * z1 + xr[lane + 128] * z2 + xr[lane + 192] * z3;
#pragma unroll
    for (int off = 32; off; off >>= 1) q += __shfl_xor(q, off, 64);
    tot[n] = q / (rn[idx] * zn);
  }
  float m = tot[0];
#pragma unroll
  for (int n = 1; n < 10; ++n) m = fmaxf(m, tot[n]);
  float se = 0.f;
#pragma unroll
  for (int n = 0; n < 10; ++n) se += expf(tot[n] - m);
  float logp0 = (tot[0] - m) - logf(se);
  float accv = (tot[0] >= m) ? 1.0f : 0.0f;  // argmax==0 iff tot[0] is the max

  if (lane == 0) { nce_s[wave] = -logp0; acc_s[wave] = accv; }
  __syncthreads();
  if (i == 0) {
    atomicAdd(accum,     nce_s[0] + nce_s[1] + nce_s[2] + nce_s[3]);
    atomicAdd(accum + 1, acc_s[0] + acc_s[1] + acc_s[2] + acc_s[3]);
  }
}

__global__ void fin_kernel(const float* __restrict__ accum,
                           float* __restrict__ out)
{
  if (threadIdx.x == 0) {
    out[(size_t)SEQ * HID]     = accum[0] / DENOMF;   // nce
    out[(size_t)SEQ * HID + 1] = accum[1] / DENOMF;   // acc
  }
}

// ---------------------------------------------------------------------------
extern "C" void kernel_launch(void* const* d_in, const int* in_sizes, int n_in,
                              void* d_out, int out_size, void* d_ws, size_t ws_size,
                              hipStream_t stream)
{
  // Inputs are f32 (reference dtypes). Output f32: z [SEQ*HID] | nce | acc.
  const float* data = (const float*)d_in[0];
  const float* Wih  = (const float*)d_in[1];
  const float* Whh  = (const float*)d_in[2];
  const float* bih  = (const float*)d_in[3];
  const float* bhh  = (const float*)d_in[4];
  float* out = (float*)d_out;

  // ws layout: xw f32 [SEQ*768] 25.17MB | wpk u32 [98304] 393KB |
  //            rn f32 [SEQ] | accum f32 [2]
  char* p = (char*)d_ws;
  float*    xw    = (float*)p;     p += (size_t)SEQ * G3 * sizeof(float);
  unsigned* wpk   = (unsigned*)p;  p += (size_t)98304 * sizeof(unsigned);
  float*    rn    = (float*)p;     p += (size_t)SEQ * sizeof(float);
  float*    accum = (float*)p;

  init_kernel<<<1, 64, 0, stream>>>(accum);
  wcvt_kernel<<<384, 256, 0, stream>>>(Whh, wpk);
  xw_kernel<<<dim3(256, 3), 256, 0, stream>>>(data, Wih, bih, xw);
  rnorm_kernel<<<SEQ / 4, 256, 0, stream>>>(data, rn);
  gru_kernel<<<1, 768, 0, stream>>>(wpk, bhh, xw, out);
  cpc_kernel<<<TCNT, 256, 0, stream>>>(data, out, rn, accum);
  fin_kernel<<<1, 1, 0, stream>>>(accum, out);
}